// Round 14
// baseline (348.964 us; speedup 1.0000x reference)
//
#include <hip/hip_runtime.h>
#include <hip/hip_bf16.h>
#include <stdint.h>

#define D_MODEL 1024
#define SEQ     2048
#define NBATCH  4
#define NHEAD   16
#define MROWS   (NBATCH*SEQ)   // 8192

typedef __attribute__((ext_vector_type(8))) short short8;
typedef __attribute__((ext_vector_type(4))) float floatx4;
typedef __attribute__((ext_vector_type(2))) unsigned int uint2v;

#if __has_builtin(__builtin_amdgcn_exp2f)
#define EXP2(x) __builtin_amdgcn_exp2f(x)
#else
#define EXP2(x) exp2f(x)
#endif

__device__ __forceinline__ unsigned short f2bf(float f) {
  unsigned int x;
  __builtin_memcpy(&x, &f, 4);
  x += 0x7fffu + ((x >> 16) & 1u);   // RNE (finite values)
  return (unsigned short)(x >> 16);
}

__device__ __forceinline__ unsigned int pk2(float a, float b) {
  __hip_bfloat162 h = __float22bfloat162_rn(make_float2(a, b));  // v_cvt_pk_bf16_f32
  unsigned int u;
  __builtin_memcpy(&u, &h, 4);
  return u;
}

__device__ __forceinline__ void gl_lds16(const unsigned short* g, unsigned short* l) {
  __builtin_amdgcn_global_load_lds(
      (const __attribute__((address_space(1))) unsigned int*)g,
      (__attribute__((address_space(3))) unsigned int*)l, 16, 0, 0);
}

// ---------------------------------------------------------------------------
// Bulk f32 -> bf16 for all 7 tensors in one dispatch (memory-bound, ~30us).
// ---------------------------------------------------------------------------
__global__ __launch_bounds__(256)
void cvt_all(const float* __restrict__ q, const float* __restrict__ k,
             const float* __restrict__ v, const float* __restrict__ wq,
             const float* __restrict__ wk, const float* __restrict__ wv,
             const float* __restrict__ wo,
             unsigned short* __restrict__ dq, unsigned short* __restrict__ dk,
             unsigned short* __restrict__ dv, unsigned short* __restrict__ dwq,
             unsigned short* __restrict__ dwk, unsigned short* __restrict__ dwv,
             unsigned short* __restrict__ dwo) {
  const unsigned QV4 = (MROWS * D_MODEL) / 4u;     // 1<<21
  const unsigned WV4 = (D_MODEL * D_MODEL) / 4u;   // 1<<18
  const unsigned total = 3u * QV4 + 4u * WV4;      // 7M
  for (unsigned i = blockIdx.x * 256u + threadIdx.x; i < total;
       i += gridDim.x * 256u) {
    const float* s;
    unsigned short* d;
    unsigned off;
    if (i < 3u * QV4) {
      const unsigned t = i >> 21;
      off = i & (QV4 - 1u);
      s = (t == 0) ? q : (t == 1) ? k : v;
      d = (t == 0) ? dq : (t == 1) ? dk : dv;
    } else {
      const unsigned j = i - 3u * QV4;
      const unsigned t = j >> 18;
      off = j & (WV4 - 1u);
      s = (t == 0) ? wq : (t == 1) ? wk : (t == 2) ? wv : wo;
      d = (t == 0) ? dwq : (t == 1) ? dwk : (t == 2) ? dwv : dwo;
    }
    const floatx4 f = *(const floatx4*)(s + (size_t)off * 4);
    uint2v u;
    u.x = pk2(f[0], f[1]);
    u.y = pk2(f[2], f[3]);
    *(uint2v*)(d + (size_t)off * 4) = u;
  }
}

// ---------------------------------------------------------------------------
// Y[M,N] = (A[M,K] @ W[N,K]^T + bias[N]) * scale, bf16 inputs.
// ROUND-3 VERIFIED STRUCTURE: 128x128 tile, BK=64, 256 threads (4 waves,
// 64x64 quadrants), 2 blocks/CU. global_load_lds staging with granule
// ROTATION. Double-buffered, 1 barrier / 64-K step.
// vtrans (V projection only): write output TRANSPOSED+PERMUTED as
// VpT[b,h][d=64][s=2048] with position p(k) within each aligned 64-key block
// equal to the VERIFIED vkap from the round-10 passing kernel (CODE, not the
// stale comment):  p(k) = ((k>>2)&3)*8 + ((k>>4)&1)*4 + (k&3) + (k>>5)*32
//                       = 32k5 + 16k3 + 8k2 + 4k4 + 2k1 + k0.
// Makes attn's V tile stageable by global_load_lds with the SAME granule-
// rotation geometry as K; PV B-fragments are bit-identical to the verified
// vkap-Vt path. [ROUND-13 BUG: used the stale-comment permutation
// (k&15)*4+(k>>4) -> absmax 0.2588, same root cause as round 9.]
// ---------------------------------------------------------------------------
template <int OMODE>
__device__ __forceinline__ void gemm_body(const unsigned short* __restrict__ A,
                                          const unsigned short* __restrict__ W,
                                          const float* __restrict__ bias,
                                          void* __restrict__ Y_,
                                          int M, int N, int K, float scale,
                                          unsigned short* As, unsigned short* Bs,
                                          int vtrans) {
  const int tid  = threadIdx.x;
  const int lane = tid & 63;
  const int w    = tid >> 6;
  const int rho  = lane & 15;
  const int quad = lane >> 4;
  const int ntile = N >> 7;
  const int cpx = gridDim.x >> 3;
  const int wg  = (blockIdx.x & 7) * cpx + (blockIdx.x >> 3);
  const int bx = wg % ntile;
  const int by = wg / ntile;
  const int tm = by << 7, tn = bx << 7;
  const int wrow = (w >> 1) << 6;
  const int wcol = (w & 1) << 6;

  const int lrow = lane >> 3;
  const int g    = ((lane & 7) - lrow) & 7;
  const unsigned short* gA = A + (size_t)(tm + w * 32 + lrow) * K + g * 8;
  const unsigned short* gB = W + (size_t)(tn + w * 32 + lrow) * K + g * 8;

  floatx4 acc[4][4] = {};

#define GSTAGE(buf, kk)                                                        \
  _Pragma("unroll") for (int c = 0; c < 4; c++) {                              \
    gl_lds16(gA + (size_t)c * 8 * K + (kk), &As[(buf)*8192 + (w*256 + c*64)*8]); \
    gl_lds16(gB + (size_t)c * 8 * K + (kk), &Bs[(buf)*8192 + (w*256 + c*64)*8]); \
  }

  GSTAGE(0, 0);
  __syncthreads();

  for (int kk = 0; kk < K; kk += 64) {
    const int cur = (kk >> 6) & 1;
    if (kk + 64 < K) { GSTAGE(cur ^ 1, kk + 64); }
    const unsigned short* as = &As[cur * 8192];
    const unsigned short* bs = &Bs[cur * 8192];
#pragma unroll
    for (int h = 0; h < 2; h++) {
      const int kp = (quad + rho + h * 4) & 7;
      short8 af[4], bf4[4];
#pragma unroll
      for (int i = 0; i < 4; i++)
        af[i] = *(const short8*)&as[(wrow + i * 16 + rho) * 64 + kp * 8];
#pragma unroll
      for (int j = 0; j < 4; j++)
        bf4[j] = *(const short8*)&bs[(wcol + j * 16 + rho) * 64 + kp * 8];
#pragma unroll
      for (int i = 0; i < 4; i++)
#pragma unroll
        for (int j = 0; j < 4; j++)
          acc[i][j] = __builtin_amdgcn_mfma_f32_16x16x32_bf16(af[i], bf4[j],
                                                              acc[i][j], 0, 0, 0);
    }
    __syncthreads();
  }
#undef GSTAGE

  float bj[4];
#pragma unroll
  for (int j = 0; j < 4; j++) bj[j] = bias[tn + wcol + j * 16 + rho];
#pragma unroll
  for (int i = 0; i < 4; i++) {
    const int grow = tm + wrow + i * 16 + (quad << 2);
#pragma unroll
    for (int j = 0; j < 4; j++) {
      const int gcol = tn + wcol + j * 16 + rho;
#pragma unroll
      for (int r = 0; r < 4; r++) {
        const float val = (acc[i][j][r] + bj[j]) * scale;
        if (OMODE == 1) {
          ((float*)Y_)[(size_t)(grow + r) * N + gcol] = val;
        } else if (vtrans) {
          // transposed+permuted V store (M=8192=4x2048, N=1024=16x64)
          const int gr  = grow + r;
          const int bq_ = gr >> 11, sq = gr & 2047;
          const int hh  = gcol >> 6, dd = gcol & 63;
          const int k6  = sq & 63;
          // TRUE verified permutation (matches round-10 vkap CODE):
          const int p   = ((k6 >> 2) & 3) * 8 + ((k6 >> 4) & 1) * 4
                        + (k6 & 3) + (k6 >> 5) * 32;
          ((unsigned short*)Y_)[(size_t)((bq_ * 16 + hh) * 64 + dd) * 2048 +
                                (sq & ~63) + p] = f2bf(val);
        } else {
          ((unsigned short*)Y_)[(size_t)(grow + r) * N + gcol] = f2bf(val);
        }
      }
    }
  }
}

template <int OMODE>
__global__ __launch_bounds__(256, 2)
void gemm_one(const unsigned short* __restrict__ A,
              const unsigned short* __restrict__ W,
              const float* __restrict__ bias, void* __restrict__ Y_,
              int M, int N, int K, float scale) {
  __shared__ __attribute__((aligned(16))) unsigned short As[2 * 128 * 64];
  __shared__ __attribute__((aligned(16))) unsigned short Bs[2 * 128 * 64];
  gemm_body<OMODE>(A, W, bias, Y_, M, N, K, scale, As, Bs, 0);
}

__global__ __launch_bounds__(256, 2)
void gemm_qkv(const unsigned short* __restrict__ qb, const unsigned short* __restrict__ wqb,
              const float* __restrict__ bq, unsigned short* __restrict__ Qp,
              const unsigned short* __restrict__ kb, const unsigned short* __restrict__ wkb,
              const float* __restrict__ bk, unsigned short* __restrict__ Kp,
              const unsigned short* __restrict__ vb, const unsigned short* __restrict__ wvb,
              const float* __restrict__ bv, unsigned short* __restrict__ Vp,
              float qscale) {
  __shared__ __attribute__((aligned(16))) unsigned short As[2 * 128 * 64];
  __shared__ __attribute__((aligned(16))) unsigned short Bs[2 * 128 * 64];
  const int y = blockIdx.y;
  const unsigned short* A = (y == 0) ? qb : (y == 1) ? kb : vb;
  const unsigned short* W = (y == 0) ? wqb : (y == 1) ? wkb : wvb;
  const float* bias       = (y == 0) ? bq : (y == 1) ? bk : bv;
  unsigned short* Y       = (y == 0) ? Qp : (y == 1) ? Kp : Vp;
  const float scale = (y == 0) ? qscale : 1.0f;
  gemm_body<0>(A, W, bias, Y, MROWS, D_MODEL, D_MODEL, scale, As, Bs,
               (y == 2) ? 1 : 0);
}

// ---------------------------------------------------------------------------
// Fused flash attention, QBLK=256, 256 threads (4 waves x 64 q-rows),
// 2 blocks/CU. Swapped QK^T (register-direct P) — round-10 verified math.
// V consumed from VpT (transposed+permuted by the V projection with the TRUE
// vkap permutation): LDS Vs[64 d][64 pos], 128B rows, granule rotation
// (content granule g stored at slot (g+d)&7). Staged by 2 global_load_lds
// per thread — the scalar V-transpose (VLOAD+VWRITE) is DELETED. bv reads at
// kp0/kp1 deliver content granule quad / quad+4 of row d: bit-identical
// fragments to the round-10 passing kernel. K unchanged. qt-major block
// mapping keeps each (b,h)'s K/V on one XCD. T5 setprio.
// ---------------------------------------------------------------------------
__device__ __forceinline__ void attn_step(const unsigned short* __restrict__ ks,
                                          const unsigned short* __restrict__ vs,
                                          const short8 (&aq)[4][2],
                                          float (&lsum)[4], floatx4 (&oacc)[4][4],
                                          int rho, int quad, int kp0, int kp1) {
  // QK^T swapped: sc[u][gk] holds S[key=gk*16+quad*4+r][q=u*16+rho]
  floatx4 sc[4][4];
  __builtin_amdgcn_s_setprio(1);
#pragma unroll
  for (int gk = 0; gk < 4; gk++) {
    const int key = gk*16 + rho;
    const short8 kf0 = *(const short8*)(ks + (key*8 + kp0)*8);
    const short8 kf1 = *(const short8*)(ks + (key*8 + kp1)*8);
#pragma unroll
    for (int u = 0; u < 4; u++) {
      floatx4 t = {0.f, 0.f, 0.f, 0.f};
      t = __builtin_amdgcn_mfma_f32_16x16x32_bf16(kf0, aq[u][0], t, 0, 0, 0);
      t = __builtin_amdgcn_mfma_f32_16x16x32_bf16(kf1, aq[u][1], t, 0, 0, 0);
      sc[u][gk] = t;
    }
  }
  __builtin_amdgcn_s_setprio(0);
  // softmax (no-max, log2 domain) + pack P directly into PV A-fragments
  short8 pa0[4], pa1[4];
#pragma unroll
  for (int u = 0; u < 4; u++) {
    float E[4][4];
#pragma unroll
    for (int gk = 0; gk < 4; gk++)
#pragma unroll
      for (int r = 0; r < 4; r++) E[gk][r] = EXP2(sc[u][gk][r]);
    float s01 = 0.f, s23 = 0.f;
#pragma unroll
    for (int r = 0; r < 4; r++) { s01 += E[0][r] + E[1][r]; s23 += E[2][r] + E[3][r]; }
    lsum[u] += s01 + s23;
    union { short8 s; unsigned int w4[4]; } a0, a1;
    a0.w4[0] = pk2(E[0][0], E[0][1]); a0.w4[1] = pk2(E[0][2], E[0][3]);
    a0.w4[2] = pk2(E[1][0], E[1][1]); a0.w4[3] = pk2(E[1][2], E[1][3]);
    a1.w4[0] = pk2(E[2][0], E[2][1]); a1.w4[1] = pk2(E[2][2], E[2][3]);
    a1.w4[2] = pk2(E[3][0], E[3][1]); a1.w4[3] = pk2(E[3][2], E[3][3]);
    pa0[u] = a0.s; pa1[u] = a1.s;
  }
  // P @ V: B-fragments straight from Vs with the K-style granule rotation
  short8 bv0[4], bv1[4];
#pragma unroll
  for (int c = 0; c < 4; c++) {
    bv0[c] = *(const short8*)&vs[(c*16 + rho)*64 + kp0*8];
    bv1[c] = *(const short8*)&vs[(c*16 + rho)*64 + kp1*8];
  }
  __builtin_amdgcn_s_setprio(1);
#pragma unroll
  for (int u = 0; u < 4; u++)
#pragma unroll
    for (int c = 0; c < 4; c++) {
      oacc[u][c] = __builtin_amdgcn_mfma_f32_16x16x32_bf16(pa0[u], bv0[c], oacc[u][c], 0, 0, 0);
      oacc[u][c] = __builtin_amdgcn_mfma_f32_16x16x32_bf16(pa1[u], bv1[c], oacc[u][c], 0, 0, 0);
    }
  __builtin_amdgcn_s_setprio(0);
}

__global__ __launch_bounds__(256, 2)
void attn_fused(const unsigned short* __restrict__ Qp,
                const unsigned short* __restrict__ Kp,
                const unsigned short* __restrict__ VpT,
                unsigned short* __restrict__ AO) {
  __shared__ unsigned short Ks[2][64*64];   // 16 KB
  __shared__ unsigned short Vs[2][64*64];   // 16 KB   (total 32 KB)

  const int tid  = threadIdx.x;
  const int w    = tid >> 6;
  const int lane = tid & 63;
  const int rho  = lane & 15;
  const int quad = lane >> 4;

  // qt-major: the 8 qt-blocks of one (b,h) share blockIdx%8 -> same XCD L2.
  const int qt = blockIdx.x >> 6;           // 8 q-tiles of 256
  const int bh = blockIdx.x & 63;
  const int b  = bh >> 4;
  const int h  = bh & 15;
  const size_t base = (size_t)b*SEQ*D_MODEL + h*64;
  const unsigned short* Qb = Qp + base;
  const unsigned short* Kb = Kp + base;
  const unsigned short* VbT = VpT + (size_t)(b*16 + h) * 64 * 2048;

  const int q0 = qt*256 + w*64;

  short8 aq[4][2];
#pragma unroll
  for (int u = 0; u < 4; u++) {
    const unsigned short* qr = Qb + (size_t)(q0 + u*16 + rho)*D_MODEL + quad*8;
    aq[u][0] = *(const short8*)qr;
    aq[u][1] = *(const short8*)(qr + 32);
  }

  float lsum[4] = {};
  floatx4 oacc[4][4] = {};

  // K staging slots (2 per thread): slot -> (key = s>>3, g = ((s&7)-key)&7)
  const int s0 = w*64 + lane;
  const int k0key = s0 >> 3, k0g = ((s0 & 7) - k0key) & 7;
  const int s1 = 256 + w*64 + lane;
  const int k1key = s1 >> 3, k1g = ((s1 & 7) - k1key) & 7;

  // V staging (2 granules/thread): G -> LDS row d = G>>3, slot = G&7,
  // content granule vg = (slot - d)&7; src = VbT + d*2048 + kb + vg*8.
  const int vr0 = s0 >> 3, vg0 = ((s0 & 7) - vr0) & 7;
  const int vr1 = s1 >> 3, vg1 = ((s1 & 7) - vr1) & 7;

  // read granule rotation (shared by K and V reads)
  const int kp0 = (quad + rho) & 7;
  const int kp1 = (kp0 + 4) & 7;

#define KSTAGE(buf, kbase)                                                     \
  { gl_lds16(Kb + (size_t)((kbase) + k0key)*D_MODEL + k0g*8, &Ks[buf][(w*64)*8]);      \
    gl_lds16(Kb + (size_t)((kbase) + k1key)*D_MODEL + k1g*8, &Ks[buf][(256 + w*64)*8]); }
#define VSTAGE(buf, kbase)                                                     \
  { gl_lds16(VbT + (size_t)vr0*2048 + (kbase) + vg0*8, &Vs[buf][(w*64)*8]);            \
    gl_lds16(VbT + (size_t)vr1*2048 + (kbase) + vg1*8, &Vs[buf][(256 + w*64)*8]); }

  KSTAGE(0, 0);
  VSTAGE(0, 0);

  for (int kb = 0; kb < SEQ; kb += 128) {
    __syncthreads();            // drains vmcnt: buf0 (K+V) staged & visible
    KSTAGE(1, kb + 64);
    VSTAGE(1, kb + 64);
    attn_step(&Ks[0][0], &Vs[0][0], aq, lsum, oacc, rho, quad, kp0, kp1);

    __syncthreads();            // drains vmcnt: buf1 staged & visible
    if (kb + 128 < SEQ) {
      KSTAGE(0, kb + 128);
      VSTAGE(0, kb + 128);
    }
    attn_step(&Ks[1][0], &Vs[1][0], aq, lsum, oacc, rho, quad, kp0, kp1);
  }
#undef KSTAGE
#undef VSTAGE

  // row-sum completion: partials live per-lane (q = u*16+rho); reduce over quad
#pragma unroll
  for (int u = 0; u < 4; u++) {
    lsum[u] += __shfl_xor(lsum[u], 16);
    lsum[u] += __shfl_xor(lsum[u], 32);
  }

#pragma unroll
  for (int u = 0; u < 4; u++) {
    float inv[4];
#pragma unroll
    for (int r = 0; r < 4; r++)
      inv[r] = 1.0f / __shfl(lsum[u], quad * 4 + r, 64);
#pragma unroll
    for (int c = 0; c < 4; c++)
#pragma unroll
      for (int r = 0; r < 4; r++)
        AO[base + (size_t)(q0 + u*16 + (quad << 2) + r)*D_MODEL + c*16 + rho] =
            f2bf(oacc[u][c][r] * inv[r]);
  }
}

extern "C" void kernel_launch(void* const* d_in, const int* in_sizes, int n_in,
                              void* d_out, int out_size, void* d_ws, size_t ws_size,
                              hipStream_t stream) {
  const float* q  = (const float*)d_in[0];
  const float* k  = (const float*)d_in[1];
  const float* v  = (const float*)d_in[2];
  const float* wq = (const float*)d_in[3];
  const float* bq = (const float*)d_in[4];
  const float* wk = (const float*)d_in[5];
  const float* bk = (const float*)d_in[6];
  const float* wv = (const float*)d_in[7];
  const float* bv = (const float*)d_in[8];
  const float* wo = (const float*)d_in[9];
  const float* bo = (const float*)d_in[10];
  float* out = (float*)d_out;

  unsigned short* Qp  = (unsigned short*)d_ws;
  unsigned short* Kp  = Qp + (size_t)MROWS*D_MODEL;
  unsigned short* Vp  = Kp + (size_t)MROWS*D_MODEL;   // holds VpT layout
  unsigned short* AO  = Vp + (size_t)MROWS*D_MODEL;
  unsigned short* qb  = AO + (size_t)MROWS*D_MODEL;
  unsigned short* kb  = qb + (size_t)MROWS*D_MODEL;
  unsigned short* vb  = kb + (size_t)MROWS*D_MODEL;
  unsigned short* wqb = vb + (size_t)MROWS*D_MODEL;
  unsigned short* wkb = wqb + (size_t)D_MODEL*D_MODEL;
  unsigned short* wvb = wkb + (size_t)D_MODEL*D_MODEL;
  unsigned short* wob = wvb + (size_t)D_MODEL*D_MODEL;

  // fold 1/sqrt(d_k) and log2(e) into Q so attention uses exp2 directly
  const float qscale = 0.125f * 1.4426950408889634f;

  const dim3 blk(256);
  cvt_all<<<dim3(2048), blk, 0, stream>>>(q, k, v, wq, wk, wv, wo,
                                          qb, kb, vb, wqb, wkb, wvb, wob);

  gemm_qkv<<<dim3((D_MODEL/128) * (MROWS/128), 3), blk, 0, stream>>>(
      qb, wqb, bq, Qp, kb, wkb, bk, Kp, vb, wvb, bv, Vp, qscale);

  attn_fused<<<dim3(NBATCH*NHEAD*(SEQ/256)), blk, 0, stream>>>(Qp, Kp, Vp, AO);

  gemm_one<1><<<dim3((D_MODEL/128) * (MROWS/128)), blk, 0, stream>>>(
      AO, wob, bo, out, MROWS, D_MODEL, D_MODEL, 1.0f);
}